// Round 14
// baseline (198.541 us; speedup 1.0000x reference)
//
#include <hip/hip_runtime.h>
#include <hip/hip_bf16.h>

#define N_NODES 50000
#define N_EDGES 1600000
#define N_GRAPHS 16
#define K_SLOTS 8
#define LATENT 4
#define HID 32
#define NBUCKET 196      // ceil(N_NODES/256), bucket = dst>>8
#define BCAP 10240       // bucket capacity (mean 8163, sigma ~90 -> 22 sigma)
#define BIN_EPB 4096     // edges per bin block
#define EBUF_CAP 8704    // csr LDS edge cache (bucket mean 8163; overflow falls back to global)

typedef __hip_bfloat16 bf16;
typedef __attribute__((ext_vector_type(8))) short short8;
typedef __attribute__((ext_vector_type(4))) float f32x4;

__device__ __forceinline__ float ldf(const void* p, long i, int isbf) {
    return isbf ? __bfloat162float(((const bf16*)p)[i]) : ((const float*)p)[i];
}
__device__ __forceinline__ int ldi(const int* p, long i, int is64) {
    return is64 ? p[2 * i] : p[i];
}
__device__ __forceinline__ short f2bs(float f) {
    bf16 h = __float2bfloat16(f);
    return *reinterpret_cast<short*>(&h);
}
__device__ __forceinline__ unsigned pk2(float a, float b) {
    __hip_bfloat162 h2 = __float22bfloat162_rn(make_float2(a, b));
    return *reinterpret_cast<unsigned*>(&h2);
}
__device__ __forceinline__ float bs2f(unsigned s) {
    union { unsigned u; float f; } cv;
    cv.u = (s & 0xFFFFu) << 16;
    return cv.f;
}
__device__ __forceinline__ float fast_silu(float v) {
    return v * __builtin_amdgcn_rcpf(1.f + __expf(-v));
}

// ---- workspace layout (4-byte elements) ----
#define WS_POOL 0                                      // 4096 (ZERO via memset)
#define WS_GFILL 4096                                  // 256 (ZERO via memset)
#define WS_ZERO_CNT 4352
#define WS_HSUM 4352                                   // N*32 f32 (zeroed by csr_kernel)
#define WS_S    (WS_HSUM + N_NODES * HID)              // N*8
#define WS_FRAGS (WS_S + N_NODES * K_SLOTS)            // 1024 dwords (2048 shorts)
#define WS_DEG  (WS_FRAGS + 1024)                      // N (fully written by csr)
#define WS_BINNED (WS_DEG + N_NODES)                   // NBUCKET*BCAP
#define WS_EDAT (WS_BINNED + NBUCKET * BCAP)           // E uints (src | dst<<16)
#define WS_FLAGS (WS_EDAT + N_EDGES)                   // 2

// ---------------- pass 1: self-detecting bin, direct scatter into block-reserved runs ----------------
// Block-exclusive global ranges (reserved via gfill) mean any 64B line of binned is
// written by <=2 blocks; intra-bucket order is irrelevant (csr re-sorts by node).
__global__ __launch_bounds__(256) void bin_kernel(
    const void* __restrict__ x, const int* __restrict__ ei,
    const void* __restrict__ w1, const void* __restrict__ w2,
    int* __restrict__ gfill, unsigned* __restrict__ binned,
    int* __restrict__ flags, short* __restrict__ frags)
{
    __shared__ int cnt[NBUCKET];
    __shared__ int lcur[NBUCKET];
    __shared__ int sflags[2];
    int t = threadIdx.x;
    // wave-0 lane-parallel dtype detection
    if (t < 64) {
        unsigned short h = ((const unsigned short*)x)[2 * t];
        unsigned e = (h >> 7) & 0xFF;
        bool sane = ((h & 0x7FFF) == 0 || (e >= 100 && e <= 141));
        unsigned long long bs = __ballot(sane);
        bool z = (ei[2 * t + 1] == 0);
        unsigned long long bz = __ballot(z);
        if (t == 0) {
            sflags[0] = (__popcll(bs) >= 32) ? 1 : 0;   // floats are bf16
            sflags[1] = (__popcll(bz) >= 60) ? 1 : 0;   // ints are int64
        }
    }
    for (int i = t; i < NBUCKET; i += 256) cnt[i] = 0;
    __syncthreads();
    const int i64 = sflags[1];
    if (blockIdx.x == 0 && t == 0) { flags[0] = sflags[0]; flags[1] = i64; }

    long e0 = (long)blockIdx.x * BIN_EPB;
    unsigned pk[16];
    if (!i64) {
#pragma unroll
        for (int kk = 0; kk < 4; kk++) {
            long e = e0 + kk * 1024 + t * 4;
            if (e < N_EDGES) {
                int4 sv = *(const int4*)(ei + e);
                int4 dv = *(const int4*)(ei + N_EDGES + e);
                pk[kk * 4 + 0] = (unsigned)sv.x | ((unsigned)dv.x << 16);
                pk[kk * 4 + 1] = (unsigned)sv.y | ((unsigned)dv.y << 16);
                pk[kk * 4 + 2] = (unsigned)sv.z | ((unsigned)dv.z << 16);
                pk[kk * 4 + 3] = (unsigned)sv.w | ((unsigned)dv.w << 16);
                atomicAdd(&cnt[dv.x >> 8], 1);
                atomicAdd(&cnt[dv.y >> 8], 1);
                atomicAdd(&cnt[dv.z >> 8], 1);
                atomicAdd(&cnt[dv.w >> 8], 1);
            } else {
                pk[kk * 4 + 0] = pk[kk * 4 + 1] = pk[kk * 4 + 2] = pk[kk * 4 + 3] = 0xFFFFFFFFu;
            }
        }
    } else {
#pragma unroll
        for (int kk = 0; kk < 8; kk++) {
            long e = e0 + kk * 512 + t * 2;
            if (e < N_EDGES) {
                int4 sv = *(const int4*)(ei + 2 * e);
                int4 dv = *(const int4*)(ei + 2 * (N_EDGES + e));
                pk[kk * 2 + 0] = (unsigned)sv.x | ((unsigned)dv.x << 16);
                pk[kk * 2 + 1] = (unsigned)sv.z | ((unsigned)dv.z << 16);
                atomicAdd(&cnt[dv.x >> 8], 1);
                atomicAdd(&cnt[dv.z >> 8], 1);
            } else {
                pk[kk * 2 + 0] = pk[kk * 2 + 1] = 0xFFFFFFFFu;
            }
        }
    }
    __syncthreads();

    // reserve global ranges; cursors start at the reserved base
    for (int i = t; i < NBUCKET; i += 256)
        lcur[i] = atomicAdd(&gfill[i], cnt[i]);
    __syncthreads();

    // direct scatter into block-reserved runs (order within bucket irrelevant)
#pragma unroll
    for (int k = 0; k < 16; k++) {
        if (pk[k] != 0xFFFFFFFFu) {
            int b = pk[k] >> 24;
            int p = atomicAdd(&lcur[b], 1);
            binned[(long)b * BCAP + p] = pk[k];
        }
    }

    // block 0, wave 0: build MFMA weight B-fragments (consumed 2 kernels later)
    if (blockIdx.x == 0 && t < 64) {
        int fbf = sflags[0];
        int nl = t & 15, quad = (t >> 4) & 3;
#pragma unroll
        for (int j = 0; j < 8; j++) {
            int k = quad * 8 + j;
            frags[(0 * 64 + t) * 8 + j] = (k < 9) ? f2bs(ldf(w1, k * 32 + nl, fbf)) : (short)0;
            frags[(1 * 64 + t) * 8 + j] = (k < 9) ? f2bs(ldf(w1, k * 32 + 16 + nl, fbf)) : (short)0;
            frags[(2 * 64 + t) * 8 + j] = f2bs(ldf(w2, k * 32 + nl, fbf));
            frags[(3 * 64 + t) * 8 + j] = f2bs(ldf(w2, k * 32 + 16 + nl, fbf));
        }
    }
}

// ---------------- pass 2: per-bucket counting sort, single global pass + LDS cache ----------------
__global__ __launch_bounds__(1024) void csr_kernel(
    const int* __restrict__ gfill, const unsigned* __restrict__ binned,
    unsigned* __restrict__ edat, int* __restrict__ deg, float* __restrict__ hsum)
{
    __shared__ unsigned ebuf[EBUF_CAP];   // 34 KB bucket cache
    __shared__ int red[16];
    __shared__ int lcnt[256], lcur[256];
    int b = blockIdx.x, t = threadIdx.x;
    int lane = t & 63;
    if (t < 256) lcnt[t] = 0;

    // base = sum(gfill[0..b-1]) via shfl reduce
    int bv = (t < 256 && t < b && t < NBUCKET) ? gfill[t] : 0;
#pragma unroll
    for (int d = 32; d > 0; d >>= 1) bv += __shfl_down(bv, d);
    if (lane == 0) red[t >> 6] = bv;
    __syncthreads();
    int base = red[0] + red[1] + red[2] + red[3];

    // zero this bucket's hsum rows (before msg_agg)
    {
        int nvalid = min(256, N_NODES - b * 256);
        if (nvalid > 0) {
            float4* hz = (float4*)(hsum + (size_t)b * 256 * HID);
            float4 z4 = make_float4(0.f, 0.f, 0.f, 0.f);
            for (int i = t; i < nvalid * 8; i += 1024) hz[i] = z4;
        }
    }
    int cnt = gfill[b];
    const unsigned* bp = binned + (long)b * BCAP;
    __syncthreads();   // lcnt zero + red reuse guard
    for (int i = t; i < cnt; i += 1024) {
        unsigned v = bp[i];
        if (i < EBUF_CAP) ebuf[i] = v;
        atomicAdd(&lcnt[(v >> 16) & 255], 1);
    }
    __syncthreads();

    // shfl scan of lcnt over 256
    int cv = (t < 256) ? lcnt[t] : 0;
    int v = cv;
#pragma unroll
    for (int d = 1; d < 64; d <<= 1) {
        int u = __shfl_up(v, d);
        if (lane >= d) v += u;
    }
    if (t < 256 && lane == 63) red[t >> 6] = v;
    __syncthreads();
    if (t < 256) {
        int add = 0;
        for (int q = 0; q < (t >> 6); q++) add += red[q];
        lcur[t] = v + add - cv;
        int n = b * 256 + t;
        if (n < N_NODES) deg[n] = cv;
    }
    __syncthreads();
    for (int i = t; i < cnt; i += 1024) {
        unsigned pk = (i < EBUF_CAP) ? ebuf[i] : bp[i];
        int pos = base + atomicAdd(&lcur[(pk >> 16) & 255], 1);
        edat[pos] = pk;
    }
}

// ---------------- MFMA msg MLP + transposed segmented reduction ----------------
__global__ __launch_bounds__(256) void msg_agg_kernel(
    const void* __restrict__ x, const void* __restrict__ pos,
    const unsigned* __restrict__ edat, const short* __restrict__ frags,
    const void* __restrict__ b1, const void* __restrict__ b2,
    float* __restrict__ hsum, const int* __restrict__ flags)
{
    const int fbf = flags[0];
    __shared__ short buf[256 * 34];    // 17 KB: A1 (stride 34) -> A2 -> msgT (32 x stride 258)
    __shared__ int sdL[256];
    __shared__ int runstart[256];
    __shared__ int wcnt[4];

    int t = threadIdx.x;
    int lane = t & 63, wv = t >> 6;
    int nl = lane & 15, quad = lane >> 4;

    const short8 w1f0 = *(const short8*)&frags[(0 * 64 + lane) * 8];
    const short8 w1f1 = *(const short8*)&frags[(1 * 64 + lane) * 8];
    const short8 w2f0 = *(const short8*)&frags[(2 * 64 + lane) * 8];
    const short8 w2f1 = *(const short8*)&frags[(3 * 64 + lane) * 8];
    float b1c0 = ldf(b1, nl, fbf), b1c1 = ldf(b1, 16 + nl, fbf);
    float b2c0 = ldf(b2, nl, fbf), b2c1 = ldf(b2, 16 + nl, fbf);

    long i = (long)blockIdx.x * 256 + t;
    unsigned ed = edat[i];
    int src = (int)(ed & 0xFFFFu);
    int dst = (int)(ed >> 16);
    sdL[t] = dst;

    float in[9];
    if (fbf) {
        const unsigned* xb = (const unsigned*)x;
        unsigned d0 = xb[dst * 2], d1 = xb[dst * 2 + 1];
        unsigned s0 = xb[src * 2], s1 = xb[src * 2 + 1];
        in[0] = bs2f(d0); in[1] = bs2f(d0 >> 16);
        in[2] = bs2f(d1); in[3] = bs2f(d1 >> 16);
        in[4] = bs2f(s0); in[5] = bs2f(s0 >> 16);
        in[6] = bs2f(s1); in[7] = bs2f(s1 >> 16);
        const unsigned short* pp = (const unsigned short*)pos;
        float dx = bs2f(pp[3 * src + 0]) - bs2f(pp[3 * dst + 0]);
        float dy = bs2f(pp[3 * src + 1]) - bs2f(pp[3 * dst + 1]);
        float dz = bs2f(pp[3 * src + 2]) - bs2f(pp[3 * dst + 2]);
        in[8] = sqrtf(dx * dx + dy * dy + dz * dz);
    } else {
        float4 xd = ((const float4*)x)[dst];
        float4 xs = ((const float4*)x)[src];
        in[0] = xd.x; in[1] = xd.y; in[2] = xd.z; in[3] = xd.w;
        in[4] = xs.x; in[5] = xs.y; in[6] = xs.z; in[7] = xs.w;
        const float* pf = (const float*)pos;
        float dx = pf[3 * src + 0] - pf[3 * dst + 0];
        float dy = pf[3 * src + 1] - pf[3 * dst + 1];
        float dz = pf[3 * src + 2] - pf[3 * dst + 2];
        in[8] = sqrtf(dx * dx + dy * dy + dz * dz);
    }

    {
        unsigned* rowp = (unsigned*)&buf[t * 34];
        rowp[0] = pk2(in[0], in[1]);
        rowp[1] = pk2(in[2], in[3]);
        rowp[2] = pk2(in[4], in[5]);
        rowp[3] = pk2(in[6], in[7]);
        rowp[4] = pk2(in[8], 0.f);
#pragma unroll
        for (int p = 5; p < 16; p++) rowp[p] = 0;
    }
    __syncthreads();

    int rb = wv * 64;
    short8 af[4];
#pragma unroll
    for (int mt = 0; mt < 4; mt++) {
        int row = rb + mt * 16 + nl;
        af[mt] = *(short8*)&buf[row * 34 + quad * 8];
    }
    __syncthreads();

    f32x4 zero = {0.f, 0.f, 0.f, 0.f};
#pragma unroll
    for (int mt = 0; mt < 4; mt++) {
        f32x4 c0 = __builtin_amdgcn_mfma_f32_16x16x32_bf16(af[mt], w1f0, zero, 0, 0, 0);
        f32x4 c1 = __builtin_amdgcn_mfma_f32_16x16x32_bf16(af[mt], w1f1, zero, 0, 0, 0);
#pragma unroll
        for (int r = 0; r < 4; r++) {
            int row = rb + mt * 16 + quad * 4 + r;
            buf[row * 34 + nl] = f2bs(fast_silu(c0[r] + b1c0));
            buf[row * 34 + 16 + nl] = f2bs(fast_silu(c1[r] + b1c1));
        }
    }
    __syncthreads();

    short8 a2f[4];
#pragma unroll
    for (int mt = 0; mt < 4; mt++) {
        int row = rb + mt * 16 + nl;
        a2f[mt] = *(short8*)&buf[row * 34 + quad * 8];
    }
    __syncthreads();

    short* msgT = buf;   // 32*258 = 8256 <= 8704 shorts
#pragma unroll
    for (int mt = 0; mt < 4; mt++) {
        f32x4 d0 = __builtin_amdgcn_mfma_f32_16x16x32_bf16(a2f[mt], w2f0, zero, 0, 0, 0);
        f32x4 d1 = __builtin_amdgcn_mfma_f32_16x16x32_bf16(a2f[mt], w2f1, zero, 0, 0, 0);
        int ob = rb + mt * 16 + quad * 4;
        unsigned* c0p = (unsigned*)&msgT[nl * 258 + ob];
        unsigned* c1p = (unsigned*)&msgT[(nl + 16) * 258 + ob];
        c0p[0] = pk2(d0[0] + b2c0, d0[1] + b2c0);
        c0p[1] = pk2(d0[2] + b2c0, d0[3] + b2c0);
        c1p[0] = pk2(d1[0] + b2c1, d1[1] + b2c1);
        c1p[1] = pk2(d1[2] + b2c1, d1[3] + b2c1);
    }
    __syncthreads();

    bool head = (t == 0) || (sdL[t] != sdL[t - 1]);
    unsigned long long bal = __ballot(head);
    if (lane == 0) wcnt[wv] = __popcll(bal);
    __syncthreads();
    int nruns = wcnt[0] + wcnt[1] + wcnt[2] + wcnt[3];
    if (head) {
        int base = 0;
        for (int q = 0; q < wv; q++) base += wcnt[q];
        int myrun = base + __popcll(bal & (((unsigned long long)1 << lane) - 1ull));
        runstart[myrun] = t;
    }
    __syncthreads();

    int g = t >> 5, c = t & 31;
    const short* col = &msgT[c * 258];
    const unsigned* colu = (const unsigned*)col;
    for (int r = g; r < nruns; r += 8) {
        int s0 = runstart[r];
        int s1 = (r + 1 < nruns) ? runstart[r + 1] : 256;
        float acc = 0.f;
        int j = s0;
        if (j & 1) { acc += bs2f((unsigned)(unsigned short)col[j]); j++; }
        for (; j + 1 < s1; j += 2) {
            unsigned d = colu[j >> 1];
            acc += bs2f(d) + bs2f(d >> 16);
        }
        if (j < s1) acc += bs2f((unsigned)(unsigned short)col[j]);
        int node = sdL[s0];
        if (s0 == 0 || s1 == 256) atomicAdd(&hsum[(size_t)node * HID + c], acc);
        else hsum[(size_t)node * HID + c] = acc;
    }
}

// ---------------- fused normalize + softmax + MFMA pooling ----------------
__global__ __launch_bounds__(256) void pool_softmax_kernel(
    const float* __restrict__ hsum, const int* __restrict__ deg,
    const int* __restrict__ batch,
    const void* __restrict__ pw, const void* __restrict__ pb,
    float* __restrict__ s, float* __restrict__ pooled,
    const int* __restrict__ flags)
{
    const int fbf = flags[0], i64 = flags[1];
    __shared__ float spw[HID * K_SLOTS], spb[K_SLOTS];
    __shared__ short hT[32 * 266];
    __shared__ short sT[16 * 266];
    __shared__ float invL[256];
    __shared__ int gL[256];
    __shared__ int runstart[16];
    __shared__ int wcnt[4];
    int t = threadIdx.x;
    int lane = t & 63, wv = t >> 6;
    int n0 = blockIdx.x * 256;
    spw[t] = ldf(pw, t, fbf);
    if (t < K_SLOTS) spb[t] = ldf(pb, t, fbf);
    for (int i = t; i < 8 * 266; i += 256) sT[8 * 266 + i] = 0;
    {
        int n = n0 + t;
        bool valid = n < N_NODES;
        gL[t] = ldi(batch, valid ? n : (N_NODES - 1), i64);
        invL[t] = valid ? __builtin_amdgcn_rcpf(fmaxf((float)deg[n], 1.f)) : 0.f;
    }
    __syncthreads();
    for (int i = t; i < 256 * HID; i += 256) {
        int node = i >> 5, c = i & 31;
        float v = ((n0 + node) < N_NODES) ? hsum[(size_t)n0 * HID + i] * invL[node] : 0.f;
        hT[c * 266 + node] = f2bs(v);
    }
    __syncthreads();

    {
        bool valid = (n0 + t) < N_NODES;
        float l[K_SLOTS];
#pragma unroll
        for (int k = 0; k < K_SLOTS; k++) l[k] = spb[k];
#pragma unroll
        for (int j = 0; j < HID; j++) {
            float v = bs2f((unsigned)(unsigned short)hT[j * 266 + t]);
#pragma unroll
            for (int k = 0; k < K_SLOTS; k++) l[k] = fmaf(v, spw[j * K_SLOTS + k], l[k]);
        }
        float mx = l[0];
#pragma unroll
        for (int k = 1; k < K_SLOTS; k++) mx = fmaxf(mx, l[k]);
        float sum = 0.f;
#pragma unroll
        for (int k = 0; k < K_SLOTS; k++) { l[k] = __expf(l[k] - mx); sum += l[k]; }
        float is = __builtin_amdgcn_rcpf(sum);
#pragma unroll
        for (int k = 0; k < K_SLOTS; k++) l[k] *= is;
        if (valid) {
            float4* sp = (float4*)(s + (size_t)(n0 + t) * K_SLOTS);
            sp[0] = make_float4(l[0], l[1], l[2], l[3]);
            sp[1] = make_float4(l[4], l[5], l[6], l[7]);
        } else {
#pragma unroll
            for (int k = 0; k < K_SLOTS; k++) l[k] = 0.f;
        }
#pragma unroll
        for (int k = 0; k < K_SLOTS; k++) sT[k * 266 + t] = f2bs(l[k]);
    }
    bool head = (t == 0) || (gL[t] != gL[t - 1]);
    unsigned long long bal = __ballot(head);
    if (lane == 0) wcnt[wv] = __popcll(bal);
    __syncthreads();
    int nruns = wcnt[0] + wcnt[1] + wcnt[2] + wcnt[3];
    if (head) {
        int base = 0;
        for (int q = 0; q < wv; q++) base += wcnt[q];
        runstart[base + __popcll(bal & (((unsigned long long)1 << lane) - 1ull))] = t;
    }
    __syncthreads();

    int nl = lane & 15, quad = lane >> 4;
    int wlo = wv * 64, whi = wlo + 64;
    f32x4 zero = {0.f, 0.f, 0.f, 0.f};
    for (int r = 0; r < nruns; r++) {
        int lo = runstart[r];
        int hi = (r + 1 < nruns) ? runstart[r + 1] : 256;
        if (whi <= lo || wlo >= hi) continue;
        bool partial = (lo > wlo) || (hi < whi);
        f32x4 acc0 = zero, acc1 = zero;
#pragma unroll
        for (int kk = 0; kk < 2; kk++) {
            int base = (wv * 2 + kk) * 32 + quad * 8;
            short8 a = *(short8*)&sT[nl * 266 + base];
            if (partial) {
#pragma unroll
                for (int j = 0; j < 8; j++) {
                    int nd = base + j;
                    if (nd < lo || nd >= hi) a[j] = 0;
                }
            }
            short8 b0 = *(short8*)&hT[nl * 266 + base];
            short8 b1 = *(short8*)&hT[(nl + 16) * 266 + base];
            acc0 = __builtin_amdgcn_mfma_f32_16x16x32_bf16(a, b0, acc0, 0, 0, 0);
            acc1 = __builtin_amdgcn_mfma_f32_16x16x32_bf16(a, b1, acc1, 0, 0, 0);
        }
        if (quad < 2) {
            int g = gL[lo];
#pragma unroll
            for (int rr = 0; rr < 4; rr++) {
                int k = quad * 4 + rr;
                atomicAdd(&pooled[g * 256 + k * 32 + nl], acc0[rr]);
                atomicAdd(&pooled[g * 256 + k * 32 + 16 + nl], acc1[rr]);
            }
        }
    }
}

// ---------------- decode (with fused z) ----------------
__global__ __launch_bounds__(256) void decode_kernel(
    const float* __restrict__ s, const float* __restrict__ pooled,
    const void* __restrict__ tw, const void* __restrict__ tb,
    const void* __restrict__ dw1, const void* __restrict__ db1,
    const void* __restrict__ dw2, const void* __restrict__ db2,
    void* __restrict__ out, const int* __restrict__ flags)
{
    const int fbf = flags[0];
    __shared__ float zb[K_SLOTS * LATENT];
    __shared__ float w1[LATENT * HID], b1s[HID], w2[HID * LATENT], b2s[LATENT];
    int b = blockIdx.y;
    int t = threadIdx.x;
    if (t < K_SLOTS * LATENT) {
        int k = t >> 2, d = t & 3;
        float acc = ldf(tb, d, fbf);
        for (int c = 0; c < HID; c++)
            acc = fmaf(pooled[b * 256 + k * 32 + c], ldf(tw, c * 4 + d, fbf), acc);
        zb[t] = acc;
    }
    if (t < LATENT * HID) w1[t] = ldf(dw1, t, fbf);
    else if (t < LATENT * HID + HID * LATENT) w2[t - LATENT * HID] = ldf(dw2, t - LATENT * HID, fbf);
    if (t < HID) b1s[t] = ldf(db1, t, fbf);
    if (t < LATENT) b2s[t] = ldf(db2, t, fbf);
    __syncthreads();

    int n = blockIdx.x * 256 + t;
    if (n >= N_NODES) return;
    const float4* sp = (const float4*)(s + (size_t)n * K_SLOTS);
    float4 s01 = sp[0], s23 = sp[1];
    float sv[K_SLOTS] = {s01.x, s01.y, s01.z, s01.w, s23.x, s23.y, s23.z, s23.w};
    float q[LATENT];
#pragma unroll
    for (int d = 0; d < LATENT; d++) {
        float a = 0.f;
#pragma unroll
        for (int k = 0; k < K_SLOTS; k++) a = fmaf(sv[k], zb[k * LATENT + d], a);
        q[d] = a;
    }
    float t1[HID];
#pragma unroll
    for (int j = 0; j < HID; j++) t1[j] = b1s[j];
#pragma unroll
    for (int d = 0; d < LATENT; d++) {
        float v = q[d];
#pragma unroll
        for (int j = 0; j < HID; j++) t1[j] = fmaf(v, w1[d * HID + j], t1[j]);
    }
#pragma unroll
    for (int j = 0; j < HID; j++) t1[j] = fast_silu(t1[j]);
    float o[LATENT];
#pragma unroll
    for (int d = 0; d < LATENT; d++) o[d] = b2s[d];
#pragma unroll
    for (int j = 0; j < HID; j++) {
        float v = t1[j];
#pragma unroll
        for (int d = 0; d < LATENT; d++) o[d] = fmaf(v, w2[j * LATENT + d], o[d]);
    }
    if (fbf) {
        union { bf16 h[4]; uint2 u; } pk;
#pragma unroll
        for (int d = 0; d < LATENT; d++) pk.h[d] = __float2bfloat16(o[d]);
        ((uint2*)out)[(size_t)b * N_NODES + n] = pk.u;
    } else {
        float4 v4 = make_float4(o[0], o[1], o[2], o[3]);
        ((float4*)out)[(size_t)b * N_NODES + n] = v4;
    }
}

extern "C" void kernel_launch(void* const* d_in, const int* in_sizes, int n_in,
                              void* d_out, int out_size, void* d_ws, size_t ws_size,
                              hipStream_t stream) {
    const void* x      = d_in[0];
    const void* pos    = d_in[1];
    const int*  ei     = (const int*)d_in[2];
    const int*  batch  = (const int*)d_in[3];
    const void* enc_w1 = d_in[4];
    const void* enc_b1 = d_in[5];
    const void* enc_w2 = d_in[6];
    const void* enc_b2 = d_in[7];
    const void* pool_w = d_in[8];
    const void* pool_b = d_in[9];
    const void* toz_w  = d_in[10];
    const void* toz_b  = d_in[11];
    const void* dec_w1 = d_in[12];
    const void* dec_b1 = d_in[13];
    const void* dec_w2 = d_in[14];
    const void* dec_b2 = d_in[15];

    float* ws = (float*)d_ws;
    float* pooled = ws + WS_POOL;
    int*   gfill  = (int*)(ws + WS_GFILL);
    float* hsum   = ws + WS_HSUM;
    float* s      = ws + WS_S;
    short* frags  = (short*)(ws + WS_FRAGS);
    int*   deg    = (int*)(ws + WS_DEG);
    unsigned* binned = (unsigned*)(ws + WS_BINNED);
    unsigned* edat   = (unsigned*)(ws + WS_EDAT);
    int*   flags  = (int*)(ws + WS_FLAGS);

    hipMemsetAsync(d_ws, 0, (size_t)WS_ZERO_CNT * 4, stream);

    int gbin = (N_EDGES + BIN_EPB - 1) / BIN_EPB;
    bin_kernel<<<gbin, 256, 0, stream>>>(x, ei, enc_w1, enc_w2, gfill, binned, flags, frags);
    csr_kernel<<<NBUCKET, 1024, 0, stream>>>(gfill, binned, edat, deg, hsum);

    msg_agg_kernel<<<N_EDGES / 256, 256, 0, stream>>>(
        x, pos, edat, frags, enc_b1, enc_b2, hsum, flags);

    pool_softmax_kernel<<<NBUCKET, 256, 0, stream>>>(
        hsum, deg, batch, pool_w, pool_b, s, pooled, flags);
    dim3 dg((N_NODES + 255) / 256, N_GRAPHS);
    decode_kernel<<<dg, 256, 0, stream>>>(
        s, pooled, toz_w, toz_b, dec_w1, dec_b1, dec_w2, dec_b2, d_out, flags);
}